// Round 2
// baseline (744.595 us; speedup 1.0000x reference)
//
#include <hip/hip_runtime.h>
#include <hip/hip_bf16.h>
#include <cstdint>

#define BB 8
#define CC 128
#define HH 128
#define WWID 128
#define HW (HH * WWID)
#define NHEADS 4
#define DC (CC / NHEADS)

typedef unsigned short u16x8 __attribute__((ext_vector_type(8)));
typedef unsigned short u16x4 __attribute__((ext_vector_type(4)));

__device__ __forceinline__ float bf2f(unsigned short u) {
  union { unsigned int i; float f; } c;
  c.i = ((unsigned int)u) << 16;
  return c.f;
}
__device__ __forceinline__ unsigned short f2bf(float f) {
  __hip_bfloat16 h = __float2bfloat16(f);
  return *reinterpret_cast<unsigned short*>(&h);
}

// ---------------------------------------------------------------------------
// 1. Per-pixel LayerNorm statistics over C=128 channels (axis 1 of B,C,H,W)
// ---------------------------------------------------------------------------
__global__ __launch_bounds__(256) void ln_stats_kernel(
    const float* __restrict__ state, const float* __restrict__ dark,
    float* __restrict__ mean_s, float* __restrict__ rstd_s,
    float* __restrict__ mean_d, float* __restrict__ rstd_d) {
  int p = blockIdx.x * 256 + threadIdx.x;
  int b = blockIdx.y;
  const float* src = (blockIdx.z == 0) ? state : dark;
  float* mo = (blockIdx.z == 0) ? mean_s : mean_d;
  float* ro = (blockIdx.z == 0) ? rstd_s : rstd_d;
  const float* base = src + (size_t)b * CC * HW + p;
  float s = 0.f, ss = 0.f;
#pragma unroll 8
  for (int c = 0; c < CC; ++c) {
    float v = base[(size_t)c * HW];
    s += v;
    ss += v * v;
  }
  float mean = s * (1.f / CC);
  float var = ss * (1.f / CC) - mean * mean;
  mo[(size_t)b * HW + p] = mean;
  ro[(size_t)b * HW + p] = rsqrtf(var + 1e-6f);
}

// ---------------------------------------------------------------------------
// 2. conv1x1 as GEMM: Out[b,o,p] = sum_c W[o,c] * Xn[b,c,p] (+ residual)
//    Xn = optionally LayerNorm'd X on the fly.
//    Tile: M=128 (all o), N=128 pixels, K-chunk 8. 256 threads, 8x8 microtile.
// ---------------------------------------------------------------------------
template <int DO_LN, int DO_RES>
__global__ __launch_bounds__(256) void conv1x1_kernel(
    const float* __restrict__ X, const float* __restrict__ Wm,
    const float* __restrict__ mean, const float* __restrict__ rstd,
    const float* __restrict__ lnw, const float* __restrict__ lnb,
    const float* __restrict__ res, float* __restrict__ Out) {
  __shared__ float Ws[8][128];  // [c_chunk][o]
  __shared__ float Xs[8][128];  // [c_chunk][p]

  int tid = threadIdx.x;
  int b = blockIdx.y;
  int p0 = blockIdx.x * 128;
  int tx = tid & 15, ty = tid >> 4;
  const size_t boff = (size_t)b * CC * HW;

  float acc[8][8];
#pragma unroll
  for (int i = 0; i < 8; ++i)
#pragma unroll
    for (int j = 0; j < 8; ++j) acc[i][j] = 0.f;

  // staging assignment (constant across k-chunks)
  int sp = (tid * 4) & 127;  // pixel offset within tile
  int sc = (tid * 4) >> 7;   // row within 8-chunk

  float4 m4 = {0, 0, 0, 0}, r4 = {0, 0, 0, 0};
  if (DO_LN) {
    m4 = *(const float4*)(mean + (size_t)b * HW + p0 + sp);
    r4 = *(const float4*)(rstd + (size_t)b * HW + p0 + sp);
  }

  for (int c0 = 0; c0 < CC; c0 += 8) {
    // stage W: Ws[ck][o] = W[o, c0+ck]  (gather; W is tiny and cache-resident)
#pragma unroll
    for (int i = 0; i < 4; ++i) {
      int idx = tid * 4 + i;
      int ck = idx >> 7;
      int o = idx & 127;
      Ws[ck][o] = Wm[o * CC + c0 + ck];
    }
    // stage X (vectorized, with optional LN)
    {
      int c = c0 + sc;
      float4 x4 = *(const float4*)(X + boff + (size_t)c * HW + p0 + sp);
      if (DO_LN) {
        float w = lnw[c], bb = lnb[c];
        x4.x = (x4.x - m4.x) * r4.x * w + bb;
        x4.y = (x4.y - m4.y) * r4.y * w + bb;
        x4.z = (x4.z - m4.z) * r4.z * w + bb;
        x4.w = (x4.w - m4.w) * r4.w * w + bb;
      }
      *(float4*)&Xs[sc][sp] = x4;
    }
    __syncthreads();
#pragma unroll
    for (int k = 0; k < 8; ++k) {
      float4 w0 = *(float4*)&Ws[k][ty * 8];
      float4 w1 = *(float4*)&Ws[k][ty * 8 + 4];
      float4 x0 = *(float4*)&Xs[k][tx * 8];
      float4 x1 = *(float4*)&Xs[k][tx * 8 + 4];
      float wv[8] = {w0.x, w0.y, w0.z, w0.w, w1.x, w1.y, w1.z, w1.w};
      float xv[8] = {x0.x, x0.y, x0.z, x0.w, x1.x, x1.y, x1.z, x1.w};
#pragma unroll
      for (int i = 0; i < 8; ++i)
#pragma unroll
        for (int j = 0; j < 8; ++j) acc[i][j] += wv[i] * xv[j];
    }
    __syncthreads();
  }

#pragma unroll
  for (int i = 0; i < 8; ++i) {
    int o = ty * 8 + i;
    size_t off = boff + (size_t)o * HW + p0 + tx * 8;
    float4 o0 = {acc[i][0], acc[i][1], acc[i][2], acc[i][3]};
    float4 o1 = {acc[i][4], acc[i][5], acc[i][6], acc[i][7]};
    if (DO_RES) {
      float4 r0 = *(const float4*)(res + off);
      float4 r1 = *(const float4*)(res + off + 4);
      o0.x += r0.x; o0.y += r0.y; o0.z += r0.z; o0.w += r0.w;
      o1.x += r1.x; o1.y += r1.y; o1.z += r1.z; o1.w += r1.w;
    }
    *(float4*)(Out + off) = o0;
    *(float4*)(Out + off + 4) = o1;
  }
}

// ---------------------------------------------------------------------------
// 3. Depthwise 3x3, SAME zero padding, fp32 in -> bf16 out.
//    One block per (b,c) plane; each thread does 4 adjacent x pixels.
// ---------------------------------------------------------------------------
__global__ __launch_bounds__(256) void dwconv_kernel(
    const float* __restrict__ X, const float* __restrict__ Wd,
    unsigned short* __restrict__ Out) {
  __shared__ float plane[HW];  // 64 KiB
  int bc = blockIdx.x;
  int c = bc & (CC - 1);
  const float* src = X + (size_t)bc * HW;
  int tid = threadIdx.x;
#pragma unroll
  for (int i = 0; i < 16; ++i) {
    int idx4 = i * 256 + tid;
    *(float4*)&plane[idx4 * 4] = *(const float4*)(src + idx4 * 4);
  }
  float w[9];
#pragma unroll
  for (int j = 0; j < 9; ++j) w[j] = Wd[c * 9 + j];
  __syncthreads();

  unsigned short* dst = Out + (size_t)bc * HW;
  for (int i = 0; i < 16; ++i) {
    int pix4 = i * 1024 + tid * 4;
    int y = pix4 >> 7, x0 = pix4 & 127;
    float s[4];
    if (y > 0 && y < HH - 1 && x0 >= 4 && x0 <= 120) {
      const float* pc = &plane[y * WWID + x0];
#pragma unroll
      for (int dx = 0; dx < 4; ++dx) {
        s[dx] = w[0] * pc[dx - WWID - 1] + w[1] * pc[dx - WWID] + w[2] * pc[dx - WWID + 1] +
                w[3] * pc[dx - 1]        + w[4] * pc[dx]        + w[5] * pc[dx + 1] +
                w[6] * pc[dx + WWID - 1] + w[7] * pc[dx + WWID] + w[8] * pc[dx + WWID + 1];
      }
    } else {
#pragma unroll
      for (int dx = 0; dx < 4; ++dx) {
        int x = x0 + dx;
        float acc = 0.f;
        for (int dy2 = -1; dy2 <= 1; ++dy2)
          for (int dx2 = -1; dx2 <= 1; ++dx2) {
            int yy = y + dy2, xx = x + dx2;
            if (yy >= 0 && yy < HH && xx >= 0 && xx < WWID)
              acc += w[(dy2 + 1) * 3 + dx2 + 1] * plane[yy * WWID + xx];
          }
        s[dx] = acc;
      }
    }
    u16x4 o;
#pragma unroll
    for (int dx = 0; dx < 4; ++dx) o[dx] = f2bf(s[dx]);
    *(u16x4*)(dst + pix4) = o;
  }
}

// ---------------------------------------------------------------------------
// 4. Row L2 norms (reciprocal) over HW for q and k (bf16 in): rnorm[b*C+c]
// ---------------------------------------------------------------------------
__global__ __launch_bounds__(256) void rownorm_kernel(
    const unsigned short* __restrict__ Q, const unsigned short* __restrict__ K,
    float* __restrict__ rq, float* __restrict__ rk) {
  int row = blockIdx.x;
  const unsigned short* src = blockIdx.y ? K : Q;
  float* dst = blockIdx.y ? rk : rq;
  const unsigned short* base = src + (size_t)row * HW;
  int tid = threadIdx.x;
  float ss = 0.f;
#pragma unroll
  for (int i = 0; i < 8; ++i) {
    u16x8 v = *(const u16x8*)(base + (i * 256 + tid) * 8);
#pragma unroll
    for (int j = 0; j < 8; ++j) {
      float f = bf2f(v[j]);
      ss += f * f;
    }
  }
#pragma unroll
  for (int m = 32; m >= 1; m >>= 1) ss += __shfl_xor(ss, m, 64);
  __shared__ float sred[4];
  if ((tid & 63) == 0) sred[tid >> 6] = ss;
  __syncthreads();
  if (tid == 0) {
    float t = sred[0] + sred[1] + sred[2] + sred[3];
    dst[row] = 1.f / fmaxf(sqrtf(t), 1e-12f);
  }
}

// ---------------------------------------------------------------------------
// 5a. QK^T partial sums: 32 K-splits of 512 pixels. part[bh][ks][ci*32+ce]
// ---------------------------------------------------------------------------
__global__ __launch_bounds__(256) void qk_partial_kernel(
    const unsigned short* __restrict__ Q, const unsigned short* __restrict__ K,
    float* __restrict__ part) {
  __shared__ float qs[32][129];
  __shared__ float ks[32][129];
  int ksid = blockIdx.x;  // 0..31, chunk of 512 pixels
  int bh = blockIdx.y;    // 0..31
  int b = bh >> 2, h = bh & 3;
  size_t base = ((size_t)b * CC + h * DC) * HW + ksid * 512;
  int tid = threadIdx.x;
  int ci0 = (tid >> 4) * 2, ce0 = (tid & 15) * 2;
  float a00 = 0, a01 = 0, a10 = 0, a11 = 0;
  for (int ch = 0; ch < 4; ++ch) {
#pragma unroll
    for (int i = 0; i < 2; ++i) {
      int idx = i * 256 + tid;          // 0..511 -> 32 rows x 16 u16x8
      int r = idx >> 4, c8 = (idx & 15) * 8;
      u16x8 qv = *(const u16x8*)(Q + base + (size_t)r * HW + ch * 128 + c8);
      u16x8 kv = *(const u16x8*)(K + base + (size_t)r * HW + ch * 128 + c8);
#pragma unroll
      for (int j = 0; j < 8; ++j) {
        qs[r][c8 + j] = bf2f(qv[j]);
        ks[r][c8 + j] = bf2f(kv[j]);
      }
    }
    __syncthreads();
    for (int p = 0; p < 128; ++p) {
      float q0 = qs[ci0][p], q1 = qs[ci0 + 1][p];
      float k0 = ks[ce0][p], k1 = ks[ce0 + 1][p];
      a00 += q0 * k0;
      a01 += q0 * k1;
      a10 += q1 * k0;
      a11 += q1 * k1;
    }
    __syncthreads();
  }
  float* o = part + ((size_t)bh * 32 + ksid) * 1024;
  o[ci0 * 32 + ce0] = a00;
  o[ci0 * 32 + ce0 + 1] = a01;
  o[(ci0 + 1) * 32 + ce0] = a10;
  o[(ci0 + 1) * 32 + ce0 + 1] = a11;
}

// ---------------------------------------------------------------------------
// 5b. Reduce partials, scale by temperature and 1/(|q||k|), softmax over e.
// ---------------------------------------------------------------------------
__global__ __launch_bounds__(1024) void softmax_kernel(
    const float* __restrict__ part, const float* __restrict__ rq,
    const float* __restrict__ rk, const float* __restrict__ temp,
    float* __restrict__ attn) {
  int bh = blockIdx.x;
  int b = bh >> 2, h = bh & 3;
  int tid = threadIdx.x;  // c*32 + e
  int c = tid >> 5, e = tid & 31;
  const float* p0 = part + (size_t)bh * 32 * 1024 + tid;
  float s = 0.f;
#pragma unroll
  for (int ks = 0; ks < 32; ++ks) s += p0[(size_t)ks * 1024];
  s *= temp[h] * rq[b * CC + h * DC + c] * rk[b * CC + h * DC + e];
  float m = s;
#pragma unroll
  for (int w2 = 16; w2 >= 1; w2 >>= 1) m = fmaxf(m, __shfl_xor(m, w2, 64));
  float pe = __expf(s - m);
  float sum = pe;
#pragma unroll
  for (int w2 = 16; w2 >= 1; w2 >>= 1) sum += __shfl_xor(sum, w2, 64);
  attn[(size_t)bh * 1024 + tid] = pe / sum;
}

// ---------------------------------------------------------------------------
// 6. out[b,h,c,p] = sum_e attn[c,e] * v[b,h,e,p]   (v bf16, out fp32)
// ---------------------------------------------------------------------------
__global__ __launch_bounds__(256) void av_kernel(
    const float* __restrict__ attn, const unsigned short* __restrict__ V,
    float* __restrict__ Out) {
  __shared__ float vs[32][260];  // 256-pixel chunk, rows 16B-aligned (260*4=1040)
  __shared__ float as[32][32];
  int pt = blockIdx.x, bh = blockIdx.y;
  int b = bh >> 2, h = bh & 3;
  size_t vbase = ((size_t)b * CC + h * DC) * HW + pt * 256;
  int tid = threadIdx.x;
#pragma unroll
  for (int i = 0; i < 4; ++i) {
    int idx = i * 256 + tid;  // 0..1023 -> 32 rows x 32 u16x8
    int r = idx >> 5, c8 = (idx & 31) * 8;
    u16x8 vv = *(const u16x8*)(V + vbase + (size_t)r * HW + c8);
#pragma unroll
    for (int j = 0; j < 8; ++j) vs[r][c8 + j] = bf2f(vv[j]);
  }
#pragma unroll
  for (int i = 0; i < 4; ++i)
    ((float*)as)[i * 256 + tid] = attn[(size_t)bh * 1024 + i * 256 + tid];
  __syncthreads();

  int cg = tid >> 6;        // wave id -> channel group of 8
  int p4 = (tid & 63) * 4;  // float4 pixel offset
  float4 acc[8];
#pragma unroll
  for (int ci = 0; ci < 8; ++ci) acc[ci] = make_float4(0.f, 0.f, 0.f, 0.f);
  for (int e = 0; e < 32; ++e) {
    float4 v4 = *(float4*)&vs[e][p4];
#pragma unroll
    for (int ci = 0; ci < 8; ++ci) {
      float a = as[cg * 8 + ci][e];
      acc[ci].x += a * v4.x;
      acc[ci].y += a * v4.y;
      acc[ci].z += a * v4.z;
      acc[ci].w += a * v4.w;
    }
  }
#pragma unroll
  for (int ci = 0; ci < 8; ++ci) {
    size_t off = ((size_t)b * CC + h * DC + cg * 8 + ci) * HW + pt * 256 + p4;
    *(float4*)(Out + off) = acc[ci];
  }
}

// ---------------------------------------------------------------------------
extern "C" void kernel_launch(void* const* d_in, const int* in_sizes, int n_in,
                              void* d_out, int out_size, void* d_ws, size_t ws_size,
                              hipStream_t stream) {
  (void)in_sizes; (void)n_in; (void)out_size; (void)ws_size;
  const float* state = (const float*)d_in[0];
  const float* dark = (const float*)d_in[1];
  const float* nq_w = (const float*)d_in[2];
  const float* nq_b = (const float*)d_in[3];
  const float* nkv_w = (const float*)d_in[4];
  const float* nkv_b = (const float*)d_in[5];
  const float* q_pw = (const float*)d_in[6];
  const float* q_dw = (const float*)d_in[7];
  const float* k_pw = (const float*)d_in[8];
  const float* k_dw = (const float*)d_in[9];
  const float* v_pw = (const float*)d_in[10];
  const float* v_dw = (const float*)d_in[11];
  const float* proj_w = (const float*)d_in[12];
  const float* temp = (const float*)d_in[13];
  float* out = (float*)d_out;

  // Workspace layout (total ~166 MiB):
  //   [0,64M)    bufP   fp32 staging (conv1x1 out / attn out)
  //   [64,96M)   bufQ   bf16
  //   [96,128M)  bufK   bf16
  //   [128,160M) bufV   bf16
  //   [160M...)  stats + partials
  char* ws = (char*)d_ws;
  float* bufP = (float*)ws;
  unsigned short* bufQ = (unsigned short*)(ws + (64ull << 20));
  unsigned short* bufK = (unsigned short*)(ws + (96ull << 20));
  unsigned short* bufV = (unsigned short*)(ws + (128ull << 20));
  char* sm = ws + (160ull << 20);
  float* mean_s = (float*)sm; sm += (size_t)BB * HW * 4;
  float* rstd_s = (float*)sm; sm += (size_t)BB * HW * 4;
  float* mean_d = (float*)sm; sm += (size_t)BB * HW * 4;
  float* rstd_d = (float*)sm; sm += (size_t)BB * HW * 4;
  float* rq = (float*)sm; sm += BB * CC * 4;
  float* rk = (float*)sm; sm += BB * CC * 4;
  float* part = (float*)sm; sm += (size_t)32 * 32 * 1024 * 4;  // 4 MiB
  float* attn = (float*)sm; sm += (size_t)32 * 1024 * 4;

  // 1. LN stats for state & dark
  ln_stats_kernel<<<dim3(HW / 256, BB, 2), 256, 0, stream>>>(
      state, dark, mean_s, rstd_s, mean_d, rstd_d);

  // 2. q path: conv1x1(LN(state)) -> dwconv -> bf16
  conv1x1_kernel<1, 0><<<dim3(HW / 128, BB), 256, 0, stream>>>(
      state, q_pw, mean_s, rstd_s, nq_w, nq_b, nullptr, bufP);
  dwconv_kernel<<<dim3(BB * CC), 256, 0, stream>>>(bufP, q_dw, bufQ);

  // 3. k path: conv1x1(LN(dark)) -> dwconv -> bf16
  conv1x1_kernel<1, 0><<<dim3(HW / 128, BB), 256, 0, stream>>>(
      dark, k_pw, mean_d, rstd_d, nkv_w, nkv_b, nullptr, bufP);
  dwconv_kernel<<<dim3(BB * CC), 256, 0, stream>>>(bufP, k_dw, bufK);

  // 4. v path: conv1x1(dark) -> dwconv -> bf16
  conv1x1_kernel<0, 0><<<dim3(HW / 128, BB), 256, 0, stream>>>(
      dark, v_pw, nullptr, nullptr, nullptr, nullptr, nullptr, bufP);
  dwconv_kernel<<<dim3(BB * CC), 256, 0, stream>>>(bufP, v_dw, bufV);

  // 5. L2 norms of q,k rows
  rownorm_kernel<<<dim3(BB * CC, 2), 256, 0, stream>>>(bufQ, bufK, rq, rk);

  // 6. attention logits + softmax
  qk_partial_kernel<<<dim3(32, BB * NHEADS), 256, 0, stream>>>(bufQ, bufK, part);
  softmax_kernel<<<dim3(BB * NHEADS), 1024, 0, stream>>>(part, rq, rk, temp, attn);

  // 7. attn @ v  (writes fp32 into bufP, which is free now)
  av_kernel<<<dim3(HW / 256, BB * NHEADS), 256, 0, stream>>>(attn, bufV, bufP);

  // 8. projection + residual
  conv1x1_kernel<0, 1><<<dim3(HW / 128, BB), 256, 0, stream>>>(
      bufP, proj_w, nullptr, nullptr, nullptr, nullptr, state, out);
}

// Round 3
// 572.728 us; speedup vs baseline: 1.3001x; 1.3001x over previous
//
#include <hip/hip_runtime.h>
#include <hip/hip_bf16.h>
#include <cstdint>

#define BB 8
#define CC 128
#define HH 128
#define WWID 128
#define HW (HH * WWID)
#define NHEADS 4
#define DC (CC / NHEADS)

typedef unsigned short u16x8 __attribute__((ext_vector_type(8)));
typedef unsigned short u16x4 __attribute__((ext_vector_type(4)));
typedef short s16x8 __attribute__((ext_vector_type(8)));
typedef float f32x4 __attribute__((ext_vector_type(4)));

__device__ __forceinline__ float bf2f(unsigned short u) {
  union { unsigned int i; float f; } c;
  c.i = ((unsigned int)u) << 16;
  return c.f;
}
__device__ __forceinline__ unsigned short f2bf(float f) {
  __hip_bfloat16 h = __float2bfloat16(f);
  return *reinterpret_cast<unsigned short*>(&h);
}

// ---------------------------------------------------------------------------
// 0. Weight prep: bf16 conversion + LayerNorm folding.
//    conv(LN(x)) = r*(W' x) - r*mu*S1 + S2,  W'=W*lnw_c, S1=sum_c W*lnw,
//    S2=sum_c W*lnb. blocks: 0=q, 1=k (rows 0-127 of Wkv), 2=v (rows 128-255),
//    3=proj. 128 threads, thread = output row o.
// ---------------------------------------------------------------------------
__global__ __launch_bounds__(128) void prep_weights_kernel(
    const float* __restrict__ q_pw, const float* __restrict__ k_pw,
    const float* __restrict__ v_pw, const float* __restrict__ proj_w,
    const float* __restrict__ nq_w, const float* __restrict__ nq_b,
    const float* __restrict__ nkv_w, const float* __restrict__ nkv_b,
    unsigned short* __restrict__ Wq, unsigned short* __restrict__ Wkv,
    unsigned short* __restrict__ Wproj, float* __restrict__ S1q,
    float* __restrict__ S2q, float* __restrict__ S1k, float* __restrict__ S2k) {
  int o = threadIdx.x;
  int which = blockIdx.x;
  if (which == 0) {
    float s1 = 0.f, s2 = 0.f;
    for (int c = 0; c < CC; ++c) {
      float w = q_pw[o * CC + c];
      float wl = w * nq_w[c];
      s1 += wl;
      s2 += w * nq_b[c];
      Wq[o * CC + c] = f2bf(wl);
    }
    S1q[o] = s1;
    S2q[o] = s2;
  } else if (which == 1) {
    float s1 = 0.f, s2 = 0.f;
    for (int c = 0; c < CC; ++c) {
      float w = k_pw[o * CC + c];
      float wl = w * nkv_w[c];
      s1 += wl;
      s2 += w * nkv_b[c];
      Wkv[o * CC + c] = f2bf(wl);
    }
    S1k[o] = s1;
    S2k[o] = s2;
  } else if (which == 2) {
    for (int c = 0; c < CC; ++c) Wkv[(128 + o) * CC + c] = f2bf(v_pw[o * CC + c]);
  } else {
    for (int c = 0; c < CC; ++c) Wproj[o * CC + c] = f2bf(proj_w[o * CC + c]);
  }
}

// ---------------------------------------------------------------------------
// 1. MFMA conv1x1: Out[b,o,p] = sum_c W[o,c] * X[b,c,p], optional LN fold,
//    optional residual, bf16 or f32 out. Block: 256 thr (4 waves), tile
//    M = MT*16 rows x N=64 pixels, K=128.
//    LDS Xs[p][c] bf16 (transposed gather-stage), XOR-swizzled (p&7)<<4.
//    MFMA 16x16x32 bf16: A row=lane&15, k=(lane>>4)*8+j (contig from W rows);
//    B col=lane&15(->p), k contig (->Xs row read); D col=lane&15(p),
//    row=(lane>>4)*4+reg.
// ---------------------------------------------------------------------------
template <int MT, int LN_ROWS, int IN_BF16, int OUT_F32, int DO_RES>
__global__ __launch_bounds__(256) void conv_mfma_kernel(
    const void* __restrict__ Xv, const unsigned short* __restrict__ Wbf,
    const float* __restrict__ S1, const float* __restrict__ S2,
    const float* __restrict__ res, unsigned short* __restrict__ Out0,
    unsigned short* __restrict__ Out1, float* __restrict__ OutF) {
  constexpr int MPW = MT / 4;  // m-subtiles per wave
  __shared__ unsigned short Xs[64 * 128];  // 16 KiB, [p][c] swizzled
  __shared__ float sstat[2][4][64];

  int tid = threadIdx.x;
  int lane = tid & 63, wid = tid >> 6;
  int p = tid & 63, qd = tid >> 6;
  int b = blockIdx.y;
  int p0 = blockIdx.x * 64;

  // ---- stage: transpose-gather X[c][p] -> Xs[p][c] (bf16), LN stats on the fly
  size_t xpix = (size_t)b * CC * HW + p0 + p;
  float s = 0.f, ss = 0.f;
#pragma unroll
  for (int chunk = 0; chunk < 4; ++chunk) {
    u16x8 vals;
#pragma unroll
    for (int j = 0; j < 8; ++j) {
      int c = chunk * 32 + qd * 8 + j;
      float x;
      if (IN_BF16) {
        unsigned short raw = ((const unsigned short*)Xv)[xpix + (size_t)c * HW];
        x = bf2f(raw);
        vals[j] = raw;
      } else {
        x = ((const float*)Xv)[xpix + (size_t)c * HW];
        vals[j] = f2bf(x);
      }
      if (LN_ROWS > 0) {
        s += x;
        ss += x * x;
      }
    }
    int colb = (chunk * 64 + qd * 16) ^ ((p & 7) << 4);
    *(u16x8*)((char*)Xs + p * 256 + colb) = vals;
  }
  if (LN_ROWS > 0) {
    sstat[0][qd][p] = s;
    sstat[1][qd][p] = ss;
  }
  __syncthreads();

  // ---- MFMA main loop over K chunks of 32
  f32x4 acc[MPW][4];
#pragma unroll
  for (int mi = 0; mi < MPW; ++mi)
#pragma unroll
    for (int n = 0; n < 4; ++n) acc[mi][n] = (f32x4){0.f, 0.f, 0.f, 0.f};

#pragma unroll
  for (int kk = 0; kk < 4; ++kk) {
    s16x8 af[MPW], bfr[4];
#pragma unroll
    for (int mi = 0; mi < MPW; ++mi) {
      int o = wid * (MPW * 16) + mi * 16 + (lane & 15);
      af[mi] = *(const s16x8*)(Wbf + (size_t)o * CC + kk * 32 + (lane >> 4) * 8);
    }
#pragma unroll
    for (int n = 0; n < 4; ++n) {
      int pp = n * 16 + (lane & 15);
      int colb = (kk * 64 + (lane >> 4) * 16) ^ ((pp & 7) << 4);
      bfr[n] = *(s16x8*)((char*)Xs + pp * 256 + colb);
    }
#pragma unroll
    for (int mi = 0; mi < MPW; ++mi)
#pragma unroll
      for (int n = 0; n < 4; ++n)
        acc[mi][n] =
            __builtin_amdgcn_mfma_f32_16x16x32_bf16(af[mi], bfr[n], acc[mi][n], 0, 0, 0);
  }

  // ---- epilogue: LN fold + store
#pragma unroll
  for (int n = 0; n < 4; ++n) {
    int pp = n * 16 + (lane & 15);
    float mu = 0.f, rr = 0.f;
    if (LN_ROWS > 0) {
      float t1 = sstat[0][0][pp] + sstat[0][1][pp] + sstat[0][2][pp] + sstat[0][3][pp];
      float t2 = sstat[1][0][pp] + sstat[1][1][pp] + sstat[1][2][pp] + sstat[1][3][pp];
      mu = t1 * (1.f / 128.f);
      float var = t2 * (1.f / 128.f) - mu * mu;
      rr = rsqrtf(var + 1e-6f);
    }
#pragma unroll
    for (int mi = 0; mi < MPW; ++mi) {
      int o_base = wid * (MPW * 16) + mi * 16;
      int oo = o_base + (lane >> 4) * 4;
      bool ln = (LN_ROWS > 0) && (o_base < LN_ROWS);
      float s1a[4] = {0.f, 0.f, 0.f, 0.f}, s2a[4] = {0.f, 0.f, 0.f, 0.f};
      if (ln) {
        float4 s1v = *(const float4*)(S1 + oo);
        float4 s2v = *(const float4*)(S2 + oo);
        s1a[0] = s1v.x; s1a[1] = s1v.y; s1a[2] = s1v.z; s1a[3] = s1v.w;
        s2a[0] = s2v.x; s2a[1] = s2v.y; s2a[2] = s2v.z; s2a[3] = s2v.w;
      }
#pragma unroll
      for (int r = 0; r < 4; ++r) {
        float v = acc[mi][n][r];
        if (ln) v = rr * (v - mu * s1a[r]) + s2a[r];
        int orow = oo + r;
        if (OUT_F32) {
          size_t off = ((size_t)b * CC + orow) * HW + p0 + pp;
          float q = v;
          if (DO_RES) q += res[off];
          OutF[off] = q;
        } else {
          unsigned short* dst = Out0;
          int od = orow;
          if (MT == 16 && orow >= 128) {
            dst = Out1;
            od = orow - 128;
          }
          dst[((size_t)b * CC + od) * HW + p0 + pp] = f2bf(v);
        }
      }
    }
  }
}

// ---------------------------------------------------------------------------
// 2. Depthwise 3x3, SAME zero padding, bf16 in -> bf16 out.
// ---------------------------------------------------------------------------
__global__ __launch_bounds__(256) void dwconv_kernel(
    const unsigned short* __restrict__ X, const float* __restrict__ Wd,
    unsigned short* __restrict__ Out) {
  __shared__ float plane[HW];  // 64 KiB
  int bc = blockIdx.x;
  int c = bc & (CC - 1);
  const unsigned short* src = X + (size_t)bc * HW;
  int tid = threadIdx.x;
#pragma unroll
  for (int i = 0; i < 8; ++i) {
    int idx8 = i * 256 + tid;
    u16x8 v = *(const u16x8*)(src + idx8 * 8);
    float4 f0 = {bf2f(v[0]), bf2f(v[1]), bf2f(v[2]), bf2f(v[3])};
    float4 f1 = {bf2f(v[4]), bf2f(v[5]), bf2f(v[6]), bf2f(v[7])};
    *(float4*)&plane[idx8 * 8] = f0;
    *(float4*)&plane[idx8 * 8 + 4] = f1;
  }
  float w[9];
#pragma unroll
  for (int j = 0; j < 9; ++j) w[j] = Wd[c * 9 + j];
  __syncthreads();

  unsigned short* dst = Out + (size_t)bc * HW;
  for (int i = 0; i < 16; ++i) {
    int pix4 = i * 1024 + tid * 4;
    int y = pix4 >> 7, x0 = pix4 & 127;
    float sacc[4];
    if (y > 0 && y < HH - 1 && x0 >= 4 && x0 <= 120) {
      const float* pc = &plane[y * WWID + x0];
#pragma unroll
      for (int dx = 0; dx < 4; ++dx) {
        sacc[dx] = w[0] * pc[dx - WWID - 1] + w[1] * pc[dx - WWID] + w[2] * pc[dx - WWID + 1] +
                   w[3] * pc[dx - 1] + w[4] * pc[dx] + w[5] * pc[dx + 1] +
                   w[6] * pc[dx + WWID - 1] + w[7] * pc[dx + WWID] + w[8] * pc[dx + WWID + 1];
      }
    } else {
#pragma unroll
      for (int dx = 0; dx < 4; ++dx) {
        int x = x0 + dx;
        float a = 0.f;
        for (int dy2 = -1; dy2 <= 1; ++dy2)
          for (int dx2 = -1; dx2 <= 1; ++dx2) {
            int yy = y + dy2, xx = x + dx2;
            if (yy >= 0 && yy < HH && xx >= 0 && xx < WWID)
              a += w[(dy2 + 1) * 3 + dx2 + 1] * plane[yy * WWID + xx];
          }
        sacc[dx] = a;
      }
    }
    u16x4 o;
#pragma unroll
    for (int dx = 0; dx < 4; ++dx) o[dx] = f2bf(sacc[dx]);
    *(u16x4*)(dst + pix4) = o;
  }
}

// ---------------------------------------------------------------------------
// 3. Row L2 norms (reciprocal) over HW for q and k (bf16 in)
// ---------------------------------------------------------------------------
__global__ __launch_bounds__(256) void rownorm_kernel(
    const unsigned short* __restrict__ Q, const unsigned short* __restrict__ K,
    float* __restrict__ rq, float* __restrict__ rk) {
  int row = blockIdx.x;
  const unsigned short* src = blockIdx.y ? K : Q;
  float* dst = blockIdx.y ? rk : rq;
  const unsigned short* base = src + (size_t)row * HW;
  int tid = threadIdx.x;
  float ss = 0.f;
#pragma unroll
  for (int i = 0; i < 8; ++i) {
    u16x8 v = *(const u16x8*)(base + (i * 256 + tid) * 8);
#pragma unroll
    for (int j = 0; j < 8; ++j) {
      float f = bf2f(v[j]);
      ss += f * f;
    }
  }
#pragma unroll
  for (int m = 32; m >= 1; m >>= 1) ss += __shfl_xor(ss, m, 64);
  __shared__ float sred[4];
  if ((tid & 63) == 0) sred[tid >> 6] = ss;
  __syncthreads();
  if (tid == 0) {
    float t = sred[0] + sred[1] + sred[2] + sred[3];
    dst[row] = 1.f / fmaxf(sqrtf(t), 1e-12f);
  }
}

// ---------------------------------------------------------------------------
// 4a. QK^T partial sums: 32 K-splits of 512 pixels.
// ---------------------------------------------------------------------------
__global__ __launch_bounds__(256) void qk_partial_kernel(
    const unsigned short* __restrict__ Q, const unsigned short* __restrict__ K,
    float* __restrict__ part) {
  __shared__ float qs[32][129];
  __shared__ float ks[32][129];
  int ksid = blockIdx.x;
  int bh = blockIdx.y;
  int b = bh >> 2, h = bh & 3;
  size_t base = ((size_t)b * CC + h * DC) * HW + ksid * 512;
  int tid = threadIdx.x;
  int ci0 = (tid >> 4) * 2, ce0 = (tid & 15) * 2;
  float a00 = 0, a01 = 0, a10 = 0, a11 = 0;
  for (int ch = 0; ch < 4; ++ch) {
#pragma unroll
    for (int i = 0; i < 2; ++i) {
      int idx = i * 256 + tid;
      int r = idx >> 4, c8 = (idx & 15) * 8;
      u16x8 qv = *(const u16x8*)(Q + base + (size_t)r * HW + ch * 128 + c8);
      u16x8 kv = *(const u16x8*)(K + base + (size_t)r * HW + ch * 128 + c8);
#pragma unroll
      for (int j = 0; j < 8; ++j) {
        qs[r][c8 + j] = bf2f(qv[j]);
        ks[r][c8 + j] = bf2f(kv[j]);
      }
    }
    __syncthreads();
    for (int p = 0; p < 128; ++p) {
      float q0 = qs[ci0][p], q1 = qs[ci0 + 1][p];
      float k0 = ks[ce0][p], k1 = ks[ce0 + 1][p];
      a00 += q0 * k0;
      a01 += q0 * k1;
      a10 += q1 * k0;
      a11 += q1 * k1;
    }
    __syncthreads();
  }
  float* o = part + ((size_t)bh * 32 + ksid) * 1024;
  o[ci0 * 32 + ce0] = a00;
  o[ci0 * 32 + ce0 + 1] = a01;
  o[(ci0 + 1) * 32 + ce0] = a10;
  o[(ci0 + 1) * 32 + ce0 + 1] = a11;
}

// ---------------------------------------------------------------------------
// 4b. Reduce partials, scale, softmax over e.
// ---------------------------------------------------------------------------
__global__ __launch_bounds__(1024) void softmax_kernel(
    const float* __restrict__ part, const float* __restrict__ rq,
    const float* __restrict__ rk, const float* __restrict__ temp,
    float* __restrict__ attn) {
  int bh = blockIdx.x;
  int b = bh >> 2, h = bh & 3;
  int tid = threadIdx.x;
  int c = tid >> 5, e = tid & 31;
  const float* p0 = part + (size_t)bh * 32 * 1024 + tid;
  float s = 0.f;
#pragma unroll
  for (int ks = 0; ks < 32; ++ks) s += p0[(size_t)ks * 1024];
  s *= temp[h] * rq[b * CC + h * DC + c] * rk[b * CC + h * DC + e];
  float m = s;
#pragma unroll
  for (int w2 = 16; w2 >= 1; w2 >>= 1) m = fmaxf(m, __shfl_xor(m, w2, 64));
  float pe = __expf(s - m);
  float sum = pe;
#pragma unroll
  for (int w2 = 16; w2 >= 1; w2 >>= 1) sum += __shfl_xor(sum, w2, 64);
  attn[(size_t)bh * 1024 + tid] = pe / sum;
}

// ---------------------------------------------------------------------------
// 5. out[b,h,c,p] = sum_e attn[c,e] * v[b,h,e,p]   (v bf16, out bf16)
// ---------------------------------------------------------------------------
__global__ __launch_bounds__(256) void av_kernel(
    const float* __restrict__ attn, const unsigned short* __restrict__ V,
    unsigned short* __restrict__ Out) {
  __shared__ float vs[32][260];
  __shared__ float as[32][32];
  int pt = blockIdx.x, bh = blockIdx.y;
  int b = bh >> 2, h = bh & 3;
  size_t vbase = ((size_t)b * CC + h * DC) * HW + pt * 256;
  int tid = threadIdx.x;
#pragma unroll
  for (int i = 0; i < 4; ++i) {
    int idx = i * 256 + tid;
    int r = idx >> 5, c8 = (idx & 31) * 8;
    u16x8 vv = *(const u16x8*)(V + vbase + (size_t)r * HW + c8);
#pragma unroll
    for (int j = 0; j < 8; ++j) vs[r][c8 + j] = bf2f(vv[j]);
  }
#pragma unroll
  for (int i = 0; i < 4; ++i)
    ((float*)as)[i * 256 + tid] = attn[(size_t)bh * 1024 + i * 256 + tid];
  __syncthreads();

  int cg = tid >> 6;
  int p4 = (tid & 63) * 4;
  float4 acc[8];
#pragma unroll
  for (int ci = 0; ci < 8; ++ci) acc[ci] = make_float4(0.f, 0.f, 0.f, 0.f);
  for (int e = 0; e < 32; ++e) {
    float4 v4 = *(float4*)&vs[e][p4];
#pragma unroll
    for (int ci = 0; ci < 8; ++ci) {
      float a = as[cg * 8 + ci][e];
      acc[ci].x += a * v4.x;
      acc[ci].y += a * v4.y;
      acc[ci].z += a * v4.z;
      acc[ci].w += a * v4.w;
    }
  }
#pragma unroll
  for (int ci = 0; ci < 8; ++ci) {
    size_t off = ((size_t)b * CC + h * DC + cg * 8 + ci) * HW + pt * 256 + p4;
    u16x4 o;
    o[0] = f2bf(acc[ci].x);
    o[1] = f2bf(acc[ci].y);
    o[2] = f2bf(acc[ci].z);
    o[3] = f2bf(acc[ci].w);
    *(u16x4*)(Out + off) = o;
  }
}

// ---------------------------------------------------------------------------
extern "C" void kernel_launch(void* const* d_in, const int* in_sizes, int n_in,
                              void* d_out, int out_size, void* d_ws, size_t ws_size,
                              hipStream_t stream) {
  (void)in_sizes; (void)n_in; (void)out_size; (void)ws_size;
  const float* state = (const float*)d_in[0];
  const float* dark = (const float*)d_in[1];
  const float* nq_w = (const float*)d_in[2];
  const float* nq_b = (const float*)d_in[3];
  const float* nkv_w = (const float*)d_in[4];
  const float* nkv_b = (const float*)d_in[5];
  const float* q_pw = (const float*)d_in[6];
  const float* q_dw = (const float*)d_in[7];
  const float* k_pw = (const float*)d_in[8];
  const float* k_dw = (const float*)d_in[9];
  const float* v_pw = (const float*)d_in[10];
  const float* v_dw = (const float*)d_in[11];
  const float* proj_w = (const float*)d_in[12];
  const float* temp = (const float*)d_in[13];
  float* out = (float*)d_out;

  // Workspace: 4 rotating 32 MiB bf16 buffers + small region (~133 MiB total)
  char* ws = (char*)d_ws;
  const size_t REG = 32ull << 20;
  unsigned short* R0 = (unsigned short*)(ws + 0 * REG);
  unsigned short* R1 = (unsigned short*)(ws + 1 * REG);
  unsigned short* R2 = (unsigned short*)(ws + 2 * REG);
  unsigned short* R3 = (unsigned short*)(ws + 3 * REG);
  char* sm = ws + 4 * REG;
  float* part = (float*)sm; sm += (size_t)32 * 32 * 1024 * 4;  // 4 MiB
  float* attn = (float*)sm; sm += (size_t)32 * 1024 * 4;
  float* rq = (float*)sm; sm += BB * CC * 4;
  float* rk = (float*)sm; sm += BB * CC * 4;
  unsigned short* Wq = (unsigned short*)sm; sm += (size_t)CC * CC * 2;
  unsigned short* Wkv = (unsigned short*)sm; sm += (size_t)2 * CC * CC * 2;
  unsigned short* Wproj = (unsigned short*)sm; sm += (size_t)CC * CC * 2;
  float* S1q = (float*)sm; sm += CC * 4;
  float* S2q = (float*)sm; sm += CC * 4;
  float* S1k = (float*)sm; sm += CC * 4;
  float* S2k = (float*)sm; sm += CC * 4;

  // 0. fold LN into weights, convert to bf16
  prep_weights_kernel<<<dim3(4), 128, 0, stream>>>(
      q_pw, k_pw, v_pw, proj_w, nq_w, nq_b, nkv_w, nkv_b, Wq, Wkv, Wproj, S1q,
      S2q, S1k, S2k);

  dim3 cgrid(HW / 64, BB);
  // 1. q conv (LN folded): state -> R0;  dwconv: R0 -> R1 (= Q)
  conv_mfma_kernel<8, 128, 0, 0, 0><<<cgrid, 256, 0, stream>>>(
      state, Wq, S1q, S2q, nullptr, R0, nullptr, nullptr);
  dwconv_kernel<<<dim3(BB * CC), 256, 0, stream>>>(R0, q_dw, R1);

  // 2. fused k+v conv: dark -> R2 (k), R3 (v); dwconv: R2->R0 (=K), R3->R2 (=V)
  conv_mfma_kernel<16, 128, 0, 0, 0><<<cgrid, 256, 0, stream>>>(
      dark, Wkv, S1k, S2k, nullptr, R2, R3, nullptr);
  dwconv_kernel<<<dim3(BB * CC), 256, 0, stream>>>(R2, k_dw, R0);
  dwconv_kernel<<<dim3(BB * CC), 256, 0, stream>>>(R3, v_dw, R2);

  // 3. L2 norms of q (R1), k (R0)
  rownorm_kernel<<<dim3(BB * CC, 2), 256, 0, stream>>>(R1, R0, rq, rk);

  // 4. attention logits + softmax
  qk_partial_kernel<<<dim3(32, BB * NHEADS), 256, 0, stream>>>(R1, R0, part);
  softmax_kernel<<<dim3(BB * NHEADS), 1024, 0, stream>>>(part, rq, rk, temp, attn);

  // 5. attn @ v (V = R2) -> R3 (bf16)
  av_kernel<<<dim3(HW / 256, BB * NHEADS), 256, 0, stream>>>(attn, R2, R3);

  // 6. projection + residual (bf16 in, f32 out)
  conv_mfma_kernel<8, 0, 1, 1, 1><<<cgrid, 256, 0, stream>>>(
      R3, Wproj, nullptr, nullptr, state, nullptr, nullptr, out);
}

// Round 5
// 468.157 us; speedup vs baseline: 1.5905x; 1.2234x over previous
//
#include <hip/hip_runtime.h>
#include <hip/hip_bf16.h>
#include <cstdint>

#define BB 8
#define CC 128
#define HH 128
#define WWID 128
#define HW (HH * WWID)
#define NHEADS 4
#define DC (CC / NHEADS)

typedef unsigned short u16x8 __attribute__((ext_vector_type(8)));
typedef unsigned short u16x4 __attribute__((ext_vector_type(4)));
typedef short s16x8 __attribute__((ext_vector_type(8)));
typedef float f32x4 __attribute__((ext_vector_type(4)));

__device__ __forceinline__ float bf2f(unsigned short u) {
  union { unsigned int i; float f; } c;
  c.i = ((unsigned int)u) << 16;
  return c.f;
}
__device__ __forceinline__ unsigned short f2bf(float f) {
  __hip_bfloat16 h = __float2bfloat16(f);
  return *reinterpret_cast<unsigned short*>(&h);
}

// 4x4 transpose across a lane quad (lanes differing in low-2 bits).
// In: lane r holds row r = (v0..v3).  Out: lane r holds column r.
__device__ __forceinline__ void quad_transpose(float& v0, float& v1, float& v2,
                                               float& v3, int r) {
  float u0 = __shfl_xor(v0, 1), u1 = __shfl_xor(v1, 1);
  float u2 = __shfl_xor(v2, 1), u3 = __shfl_xor(v3, 1);
  if ((r & 1) == 0) { v1 = u0; v3 = u2; } else { v0 = u1; v2 = u3; }
  u0 = __shfl_xor(v0, 2); u1 = __shfl_xor(v1, 2);
  u2 = __shfl_xor(v2, 2); u3 = __shfl_xor(v3, 2);
  if ((r & 2) == 0) { v2 = u0; v3 = u1; } else { v0 = u2; v1 = u3; }
}

// ---------------------------------------------------------------------------
// 0. Weight prep: bf16 conversion + LayerNorm folding.
// ---------------------------------------------------------------------------
__global__ __launch_bounds__(128) void prep_weights_kernel(
    const float* __restrict__ q_pw, const float* __restrict__ k_pw,
    const float* __restrict__ v_pw, const float* __restrict__ proj_w,
    const float* __restrict__ nq_w, const float* __restrict__ nq_b,
    const float* __restrict__ nkv_w, const float* __restrict__ nkv_b,
    unsigned short* __restrict__ Wq, unsigned short* __restrict__ Wkv,
    unsigned short* __restrict__ Wproj, float* __restrict__ S1q,
    float* __restrict__ S2q, float* __restrict__ S1k, float* __restrict__ S2k) {
  int o = threadIdx.x;
  int which = blockIdx.x;
  if (which == 0) {
    float s1 = 0.f, s2 = 0.f;
    for (int c = 0; c < CC; ++c) {
      float w = q_pw[o * CC + c];
      float wl = w * nq_w[c];
      s1 += wl;
      s2 += w * nq_b[c];
      Wq[o * CC + c] = f2bf(wl);
    }
    S1q[o] = s1;
    S2q[o] = s2;
  } else if (which == 1) {
    float s1 = 0.f, s2 = 0.f;
    for (int c = 0; c < CC; ++c) {
      float w = k_pw[o * CC + c];
      float wl = w * nkv_w[c];
      s1 += wl;
      s2 += w * nkv_b[c];
      Wkv[o * CC + c] = f2bf(wl);
    }
    S1k[o] = s1;
    S2k[o] = s2;
  } else if (which == 2) {
    for (int c = 0; c < CC; ++c) Wkv[(128 + o) * CC + c] = f2bf(v_pw[o * CC + c]);
  } else {
    for (int c = 0; c < CC; ++c) Wproj[o * CC + c] = f2bf(proj_w[o * CC + c]);
  }
}

// ---------------------------------------------------------------------------
// 1. MFMA conv1x1.  Tile: M = MT*16 rows x N=64 px, K=128.
//    Staging: float4/u16x4 coalesced loads + quad shuffle-transpose ->
//    vector LDS writes into swizzled Xs[p][c].
//    Epilogue: quad shuffle-transpose of acc -> vector global stores.
// ---------------------------------------------------------------------------
template <int MT, int LN_ROWS, int IN_BF16, int OUT_F32, int DO_RES>
__global__ __launch_bounds__(256) void conv_mfma_kernel(
    const void* __restrict__ Xv, const unsigned short* __restrict__ Wbf,
    const float* __restrict__ S1, const float* __restrict__ S2,
    const float* __restrict__ res, unsigned short* __restrict__ Out0,
    unsigned short* __restrict__ Out1, float* __restrict__ OutF) {
  constexpr int MPW = MT / 4;  // 16-row subtiles per wave
  __shared__ unsigned short Xs[64 * 128];  // [p][c] bf16, swizzled (p&7)<<4
  __shared__ float sstat[2][4][64];
  __shared__ float muA[64], rrA[64];

  int tid = threadIdx.x;
  int lane = tid & 63, wid = tid >> 6;
  int b = blockIdx.y;
  int p0 = blockIdx.x * 64;

  // ---- staging
  int r = tid & 3;          // quad lane
  int pg = (tid >> 2) & 15; // pixel group of 4
  float s = 0.f, ss = 0.f;
  size_t xbase = (size_t)b * CC * HW + p0 + pg * 4;
#pragma unroll
  for (int i = 0; i < 8; ++i) {
    int cb = i * 16 + wid * 4;  // quad channel base
    int ch = cb + r;
    float v0, v1, v2, v3;
    if (IN_BF16) {
      u16x4 u = *(const u16x4*)((const unsigned short*)Xv + xbase + (size_t)ch * HW);
      v0 = bf2f(u[0]); v1 = bf2f(u[1]); v2 = bf2f(u[2]); v3 = bf2f(u[3]);
    } else {
      float4 f = *(const float4*)((const float*)Xv + xbase + (size_t)ch * HW);
      v0 = f.x; v1 = f.y; v2 = f.z; v3 = f.w;
    }
    quad_transpose(v0, v1, v2, v3, r);
    // lane now holds pixel p = pg*4 + r, channels cb..cb+3
    if (LN_ROWS > 0) {
      s += v0 + v1 + v2 + v3;
      ss += v0 * v0 + v1 * v1 + v2 * v2 + v3 * v3;
    }
    int p = pg * 4 + r;
    u16x4 o;
    o[0] = f2bf(v0); o[1] = f2bf(v1); o[2] = f2bf(v2); o[3] = f2bf(v3);
    *(u16x4*)((char*)Xs + p * 256 + ((cb * 2) ^ ((p & 7) << 4))) = o;
  }
  if (LN_ROWS > 0) {
    int p = pg * 4 + r;
    sstat[0][wid][p] = s;
    sstat[1][wid][p] = ss;
  }
  __syncthreads();

  if (LN_ROWS > 0 && wid == 0) {
    float t1 = sstat[0][0][lane] + sstat[0][1][lane] + sstat[0][2][lane] + sstat[0][3][lane];
    float t2 = sstat[1][0][lane] + sstat[1][1][lane] + sstat[1][2][lane] + sstat[1][3][lane];
    float mu = t1 * (1.f / 128.f);
    float var = t2 * (1.f / 128.f) - mu * mu;
    muA[lane] = mu;
    rrA[lane] = rsqrtf(var + 1e-6f);
  }

  // ---- MFMA main loop (K = 128, chunks of 32)
  f32x4 acc[MPW][4];
#pragma unroll
  for (int mi = 0; mi < MPW; ++mi)
#pragma unroll
    for (int n = 0; n < 4; ++n) acc[mi][n] = (f32x4){0.f, 0.f, 0.f, 0.f};

#pragma unroll
  for (int kk = 0; kk < 4; ++kk) {
    s16x8 af[MPW], bfr[4];
#pragma unroll
    for (int mi = 0; mi < MPW; ++mi) {
      int o = wid * (MPW * 16) + mi * 16 + (lane & 15);
      af[mi] = *(const s16x8*)(Wbf + (size_t)o * CC + kk * 32 + (lane >> 4) * 8);
    }
#pragma unroll
    for (int n = 0; n < 4; ++n) {
      int pp = n * 16 + (lane & 15);
      int colb = (kk * 64 + (lane >> 4) * 16) ^ ((pp & 7) << 4);
      bfr[n] = *(s16x8*)((char*)Xs + pp * 256 + colb);
    }
#pragma unroll
    for (int mi = 0; mi < MPW; ++mi)
#pragma unroll
      for (int n = 0; n < 4; ++n)
        acc[mi][n] =
            __builtin_amdgcn_mfma_f32_16x16x32_bf16(af[mi], bfr[n], acc[mi][n], 0, 0, 0);
  }

  if (LN_ROWS > 0) __syncthreads();  // muA/rrA ready

  // ---- epilogue: transpose acc quads -> vector stores
  int q = (lane >> 2) & 3, m = lane & 3, g = lane >> 4;
#pragma unroll
  for (int mi = 0; mi < MPW; ++mi) {
    int o_base = wid * (MPW * 16) + mi * 16;
    int o = o_base + g * 4 + m;
    bool ln = (LN_ROWS > 0) && (o_base < LN_ROWS);
    float s1v = 0.f, s2v = 0.f;
    if (ln) { s1v = S1[o]; s2v = S2[o]; }
#pragma unroll
    for (int n = 0; n < 4; ++n) {
      float v0 = acc[mi][n][0], v1 = acc[mi][n][1], v2 = acc[mi][n][2], v3 = acc[mi][n][3];
      quad_transpose(v0, v1, v2, v3, m);
      int px0 = n * 16 + q * 4;  // 4 consecutive pixels of row o
      if (ln) {
        float4 muv = *(float4*)&muA[px0];
        float4 rrv = *(float4*)&rrA[px0];
        v0 = rrv.x * (v0 - muv.x * s1v) + s2v;
        v1 = rrv.y * (v1 - muv.y * s1v) + s2v;
        v2 = rrv.z * (v2 - muv.z * s1v) + s2v;
        v3 = rrv.w * (v3 - muv.w * s1v) + s2v;
      }
      if (OUT_F32) {
        size_t off = ((size_t)b * CC + o) * HW + p0 + px0;
        if (DO_RES) {
          float4 rv = *(const float4*)(res + off);
          v0 += rv.x; v1 += rv.y; v2 += rv.z; v3 += rv.w;
        }
        float4 ov = {v0, v1, v2, v3};
        *(float4*)(OutF + off) = ov;
      } else {
        unsigned short* dst = Out0;
        int od = o;
        if (MT == 16 && o >= 128) { dst = Out1; od = o - 128; }
        u16x4 ov;
        ov[0] = f2bf(v0); ov[1] = f2bf(v1); ov[2] = f2bf(v2); ov[3] = f2bf(v3);
        *(u16x4*)(dst + ((size_t)b * CC + od) * HW + p0 + px0) = ov;
      }
    }
  }
}

// ---------------------------------------------------------------------------
// 2. Depthwise 3x3, strip-tiled (32 rows + halo), bf16 -> bf16.
//    NORM!=0: fuse sum-of-squares reduction (atomicAdd into normOut[bc]).
// ---------------------------------------------------------------------------
template <int NORM>
__global__ __launch_bounds__(256) void dwconv_kernel(
    const unsigned short* __restrict__ X, const float* __restrict__ Wd,
    unsigned short* __restrict__ Out, float* __restrict__ normOut) {
  __shared__ float plane[34 * 128];  // 17 KiB
  int strip = blockIdx.x & 3;
  int bc = blockIdx.x >> 2;
  int c = bc & (CC - 1);
  int y0 = strip * 32;
  const unsigned short* src = X + (size_t)bc * HW;
  int tid = threadIdx.x;

  for (int idx = tid; idx < 34 * 16; idx += 256) {
    int row = idx >> 4;
    int x8 = (idx & 15) * 8;
    int y = y0 - 1 + row;
    float4 f0 = {0, 0, 0, 0}, f1 = {0, 0, 0, 0};
    if (y >= 0 && y < HH) {
      u16x8 v = *(const u16x8*)(src + (size_t)y * WWID + x8);
      f0 = make_float4(bf2f(v[0]), bf2f(v[1]), bf2f(v[2]), bf2f(v[3]));
      f1 = make_float4(bf2f(v[4]), bf2f(v[5]), bf2f(v[6]), bf2f(v[7]));
    }
    *(float4*)&plane[row * 128 + x8] = f0;
    *(float4*)&plane[row * 128 + x8 + 4] = f1;
  }
  float w[9];
#pragma unroll
  for (int j = 0; j < 9; ++j) w[j] = Wd[c * 9 + j];
  __syncthreads();

  float ssq = 0.f;
  unsigned short* dst = Out + (size_t)bc * HW + y0 * WWID;
#pragma unroll
  for (int i = 0; i < 4; ++i) {
    int pix4 = i * 1024 + tid * 4;
    int ly = pix4 >> 7, x0 = pix4 & 127;
    const float* pc = &plane[(ly + 1) * 128 + x0];
    float sv[4];
    if (x0 >= 4 && x0 <= 120) {
#pragma unroll
      for (int dx = 0; dx < 4; ++dx)
        sv[dx] = w[0] * pc[dx - 129] + w[1] * pc[dx - 128] + w[2] * pc[dx - 127] +
                 w[3] * pc[dx - 1] + w[4] * pc[dx] + w[5] * pc[dx + 1] +
                 w[6] * pc[dx + 127] + w[7] * pc[dx + 128] + w[8] * pc[dx + 129];
    } else {
#pragma unroll
      for (int dx = 0; dx < 4; ++dx) {
        int x = x0 + dx;
        float a = 0.f;
        for (int dy = -1; dy <= 1; ++dy)
          for (int dx2 = -1; dx2 <= 1; ++dx2) {
            int xx = x + dx2;
            if (xx >= 0 && xx < WWID)
              a += w[(dy + 1) * 3 + dx2 + 1] * plane[(ly + 1 + dy) * 128 + xx];
          }
        sv[dx] = a;
      }
    }
    if (NORM) ssq += sv[0] * sv[0] + sv[1] * sv[1] + sv[2] * sv[2] + sv[3] * sv[3];
    u16x4 o;
#pragma unroll
    for (int dx = 0; dx < 4; ++dx) o[dx] = f2bf(sv[dx]);
    *(u16x4*)(dst + pix4) = o;
  }
  if (NORM) {
#pragma unroll
    for (int m2 = 32; m2 >= 1; m2 >>= 1) ssq += __shfl_xor(ssq, m2, 64);
    __shared__ float sred[4];
    if ((tid & 63) == 0) sred[tid >> 6] = ssq;
    __syncthreads();
    if (tid == 0) atomicAdd(&normOut[bc], sred[0] + sred[1] + sred[2] + sred[3]);
  }
}

// ---------------------------------------------------------------------------
// 3a. QK^T partial sums: 32 K-splits of 512 pixels.
// ---------------------------------------------------------------------------
__global__ __launch_bounds__(256) void qk_partial_kernel(
    const unsigned short* __restrict__ Q, const unsigned short* __restrict__ K,
    float* __restrict__ part) {
  __shared__ float qs[32][129];
  __shared__ float ks[32][129];
  int ksid = blockIdx.x;
  int bh = blockIdx.y;
  int b = bh >> 2, h = bh & 3;
  size_t base = ((size_t)b * CC + h * DC) * HW + ksid * 512;
  int tid = threadIdx.x;
  int ci0 = (tid >> 4) * 2, ce0 = (tid & 15) * 2;
  float a00 = 0, a01 = 0, a10 = 0, a11 = 0;
  for (int ch = 0; ch < 4; ++ch) {
#pragma unroll
    for (int i = 0; i < 2; ++i) {
      int idx = i * 256 + tid;
      int rr = idx >> 4, c8 = (idx & 15) * 8;
      u16x8 qv = *(const u16x8*)(Q + base + (size_t)rr * HW + ch * 128 + c8);
      u16x8 kv = *(const u16x8*)(K + base + (size_t)rr * HW + ch * 128 + c8);
#pragma unroll
      for (int j = 0; j < 8; ++j) {
        qs[rr][c8 + j] = bf2f(qv[j]);
        ks[rr][c8 + j] = bf2f(kv[j]);
      }
    }
    __syncthreads();
    for (int p = 0; p < 128; ++p) {
      float q0 = qs[ci0][p], q1 = qs[ci0 + 1][p];
      float k0 = ks[ce0][p], k1 = ks[ce0 + 1][p];
      a00 += q0 * k0;
      a01 += q0 * k1;
      a10 += q1 * k0;
      a11 += q1 * k1;
    }
    __syncthreads();
  }
  float* o = part + ((size_t)bh * 32 + ksid) * 1024;
  o[ci0 * 32 + ce0] = a00;
  o[ci0 * 32 + ce0 + 1] = a01;
  o[(ci0 + 1) * 32 + ce0] = a10;
  o[(ci0 + 1) * 32 + ce0 + 1] = a11;
}

// ---------------------------------------------------------------------------
// 3b. Reduce partials, scale by temp * rsqrt(ssq_q) * rsqrt(ssq_k), softmax.
// ---------------------------------------------------------------------------
__global__ __launch_bounds__(1024) void softmax_kernel(
    const float* __restrict__ part, const float* __restrict__ rq,
    const float* __restrict__ rk, const float* __restrict__ temp,
    float* __restrict__ attn) {
  int bh = blockIdx.x;
  int b = bh >> 2, h = bh & 3;
  int tid = threadIdx.x;
  int c = tid >> 5, e = tid & 31;
  const float* p0 = part + (size_t)bh * 32 * 1024 + tid;
  float s = 0.f;
#pragma unroll
  for (int ks = 0; ks < 32; ++ks) s += p0[(size_t)ks * 1024];
  float nq = sqrtf(rq[b * CC + h * DC + c]);
  float nk = sqrtf(rk[b * CC + h * DC + e]);
  s *= temp[h] / (fmaxf(nq, 1e-12f) * fmaxf(nk, 1e-12f));
  float m = s;
#pragma unroll
  for (int w2 = 16; w2 >= 1; w2 >>= 1) m = fmaxf(m, __shfl_xor(m, w2, 64));
  float pe = __expf(s - m);
  float sum = pe;
#pragma unroll
  for (int w2 = 16; w2 >= 1; w2 >>= 1) sum += __shfl_xor(sum, w2, 64);
  attn[(size_t)bh * 1024 + tid] = pe / sum;
}

// ---------------------------------------------------------------------------
// 4. out[b,h,c,p] = sum_e attn[c,e] * v[b,h,e,p]   (v bf16, out bf16)
// ---------------------------------------------------------------------------
__global__ __launch_bounds__(256) void av_kernel(
    const float* __restrict__ attn, const unsigned short* __restrict__ V,
    unsigned short* __restrict__ Out) {
  __shared__ float vs[32][260];
  __shared__ float as[32][32];
  int pt = blockIdx.x, bh = blockIdx.y;
  int b = bh >> 2, h = bh & 3;
  size_t vbase = ((size_t)b * CC + h * DC) * HW + pt * 256;
  int tid = threadIdx.x;
#pragma unroll
  for (int i = 0; i < 4; ++i) {
    int idx = i * 256 + tid;
    int rr = idx >> 5, c8 = (idx & 31) * 8;
    u16x8 vv = *(const u16x8*)(V + vbase + (size_t)rr * HW + c8);
#pragma unroll
    for (int j = 0; j < 8; ++j) vs[rr][c8 + j] = bf2f(vv[j]);
  }
#pragma unroll
  for (int i = 0; i < 4; ++i)
    ((float*)as)[i * 256 + tid] = attn[(size_t)bh * 1024 + i * 256 + tid];
  __syncthreads();

  int cg = tid >> 6;
  int p4 = (tid & 63) * 4;
  float4 acc[8];
#pragma unroll
  for (int ci = 0; ci < 8; ++ci) acc[ci] = make_float4(0.f, 0.f, 0.f, 0.f);
  for (int e = 0; e < 32; ++e) {
    float4 v4 = *(float4*)&vs[e][p4];
#pragma unroll
    for (int ci = 0; ci < 8; ++ci) {
      float a = as[cg * 8 + ci][e];
      acc[ci].x += a * v4.x;
      acc[ci].y += a * v4.y;
      acc[ci].z += a * v4.z;
      acc[ci].w += a * v4.w;
    }
  }
#pragma unroll
  for (int ci = 0; ci < 8; ++ci) {
    size_t off = ((size_t)b * CC + h * DC + cg * 8 + ci) * HW + pt * 256 + p4;
    u16x4 o;
    o[0] = f2bf(acc[ci].x);
    o[1] = f2bf(acc[ci].y);
    o[2] = f2bf(acc[ci].z);
    o[3] = f2bf(acc[ci].w);
    *(u16x4*)(Out + off) = o;
  }
}

// ---------------------------------------------------------------------------
extern "C" void kernel_launch(void* const* d_in, const int* in_sizes, int n_in,
                              void* d_out, int out_size, void* d_ws, size_t ws_size,
                              hipStream_t stream) {
  (void)in_sizes; (void)n_in; (void)out_size; (void)ws_size;
  const float* state = (const float*)d_in[0];
  const float* dark = (const float*)d_in[1];
  const float* nq_w = (const float*)d_in[2];
  const float* nq_b = (const float*)d_in[3];
  const float* nkv_w = (const float*)d_in[4];
  const float* nkv_b = (const float*)d_in[5];
  const float* q_pw = (const float*)d_in[6];
  const float* q_dw = (const float*)d_in[7];
  const float* k_pw = (const float*)d_in[8];
  const float* k_dw = (const float*)d_in[9];
  const float* v_pw = (const float*)d_in[10];
  const float* v_dw = (const float*)d_in[11];
  const float* proj_w = (const float*)d_in[12];
  const float* temp = (const float*)d_in[13];
  float* out = (float*)d_out;

  char* ws = (char*)d_ws;
  const size_t REG = 32ull << 20;
  unsigned short* R0 = (unsigned short*)(ws + 0 * REG);
  unsigned short* R1 = (unsigned short*)(ws + 1 * REG);
  unsigned short* R2 = (unsigned short*)(ws + 2 * REG);
  unsigned short* R3 = (unsigned short*)(ws + 3 * REG);
  char* sm = ws + 4 * REG;
  float* part = (float*)sm; sm += (size_t)32 * 32 * 1024 * 4;  // 4 MiB
  float* attn = (float*)sm; sm += (size_t)32 * 1024 * 4;
  float* rq = (float*)sm; sm += BB * CC * 4;  // sumsq(q) per row
  float* rk = (float*)sm; sm += BB * CC * 4;  // sumsq(k) per row
  unsigned short* Wq = (unsigned short*)sm; sm += (size_t)CC * CC * 2;
  unsigned short* Wkv = (unsigned short*)sm; sm += (size_t)2 * CC * CC * 2;
  unsigned short* Wproj = (unsigned short*)sm; sm += (size_t)CC * CC * 2;
  float* S1q = (float*)sm; sm += CC * 4;
  float* S2q = (float*)sm; sm += CC * 4;
  float* S1k = (float*)sm; sm += CC * 4;
  float* S2k = (float*)sm; sm += CC * 4;

  // zero the fused-norm accumulators (rq, rk are adjacent)
  hipMemsetAsync(rq, 0, 2 * BB * CC * sizeof(float), stream);

  prep_weights_kernel<<<dim3(4), 128, 0, stream>>>(
      q_pw, k_pw, v_pw, proj_w, nq_w, nq_b, nkv_w, nkv_b, Wq, Wkv, Wproj, S1q,
      S2q, S1k, S2k);

  dim3 cgrid(HW / 64, BB);
  // q path: conv1x1(LN(state)) -> dwconv (+|q|^2)
  conv_mfma_kernel<8, 128, 0, 0, 0><<<cgrid, 256, 0, stream>>>(
      state, Wq, S1q, S2q, nullptr, R0, nullptr, nullptr);
  dwconv_kernel<1><<<dim3(BB * CC * 4), 256, 0, stream>>>(R0, q_dw, R1, rq);

  // k+v fused conv, then dwconvs (+|k|^2 for k)
  conv_mfma_kernel<16, 128, 0, 0, 0><<<cgrid, 256, 0, stream>>>(
      dark, Wkv, S1k, S2k, nullptr, R2, R3, nullptr);
  dwconv_kernel<1><<<dim3(BB * CC * 4), 256, 0, stream>>>(R2, k_dw, R0, rk);
  dwconv_kernel<0><<<dim3(BB * CC * 4), 256, 0, stream>>>(R3, v_dw, R2, nullptr);

  // attention logits + softmax
  qk_partial_kernel<<<dim3(32, BB * NHEADS), 256, 0, stream>>>(R1, R0, part);
  softmax_kernel<<<dim3(BB * NHEADS), 1024, 0, stream>>>(part, rq, rk, temp, attn);

  // attn @ v -> R3
  av_kernel<<<dim3(HW / 256, BB * NHEADS), 256, 0, stream>>>(attn, R2, R3);

  // projection + residual (bf16 in, f32 out)
  conv_mfma_kernel<8, 0, 1, 1, 1><<<cgrid, 256, 0, stream>>>(
      R3, Wproj, nullptr, nullptr, state, nullptr, nullptr, out);
}

// Round 8
// 458.234 us; speedup vs baseline: 1.6249x; 1.0217x over previous
//
#include <hip/hip_runtime.h>
#include <hip/hip_bf16.h>
#include <cstdint>

#define BB 8
#define CC 128
#define HH 128
#define WWID 128
#define HW (HH * WWID)
#define NHEADS 4
#define DC (CC / NHEADS)

typedef unsigned short u16x8 __attribute__((ext_vector_type(8)));
typedef unsigned short u16x4 __attribute__((ext_vector_type(4)));
typedef short s16x8 __attribute__((ext_vector_type(8)));
typedef float f32x4 __attribute__((ext_vector_type(4)));

__device__ __forceinline__ float bf2f(unsigned short u) {
  union { unsigned int i; float f; } c;
  c.i = ((unsigned int)u) << 16;
  return c.f;
}
__device__ __forceinline__ unsigned short f2bf(float f) {
  __hip_bfloat16 h = __float2bfloat16(f);
  return *reinterpret_cast<unsigned short*>(&h);
}

// 4x4 transpose across a lane quad (lanes differing in low-2 bits).
__device__ __forceinline__ void quad_transpose(float& v0, float& v1, float& v2,
                                               float& v3, int r) {
  float u0 = __shfl_xor(v0, 1), u1 = __shfl_xor(v1, 1);
  float u2 = __shfl_xor(v2, 1), u3 = __shfl_xor(v3, 1);
  if ((r & 1) == 0) { v1 = u0; v3 = u2; } else { v0 = u1; v2 = u3; }
  u0 = __shfl_xor(v0, 2); u1 = __shfl_xor(v1, 2);
  u2 = __shfl_xor(v2, 2); u3 = __shfl_xor(v3, 2);
  if ((r & 2) == 0) { v2 = u0; v3 = u1; } else { v0 = u2; v1 = u3; }
}

// ---------------------------------------------------------------------------
// 0. Weight prep: bf16 + LN folding. which: 0=q,1=k,2=v,3=proj
// ---------------------------------------------------------------------------
__global__ __launch_bounds__(128) void prep_weights_kernel(
    const float* __restrict__ q_pw, const float* __restrict__ k_pw,
    const float* __restrict__ v_pw, const float* __restrict__ proj_w,
    const float* __restrict__ nq_w, const float* __restrict__ nq_b,
    const float* __restrict__ nkv_w, const float* __restrict__ nkv_b,
    unsigned short* __restrict__ Wq, unsigned short* __restrict__ Wk,
    unsigned short* __restrict__ Wv, unsigned short* __restrict__ Wproj,
    float* __restrict__ S1q, float* __restrict__ S2q, float* __restrict__ S1k,
    float* __restrict__ S2k) {
  int o = threadIdx.x;
  int which = blockIdx.x;
  if (which == 0) {
    float s1 = 0.f, s2 = 0.f;
    for (int c = 0; c < CC; ++c) {
      float w = q_pw[o * CC + c];
      float wl = w * nq_w[c];
      s1 += wl;
      s2 += w * nq_b[c];
      Wq[o * CC + c] = f2bf(wl);
    }
    S1q[o] = s1;
    S2q[o] = s2;
  } else if (which == 1) {
    float s1 = 0.f, s2 = 0.f;
    for (int c = 0; c < CC; ++c) {
      float w = k_pw[o * CC + c];
      float wl = w * nkv_w[c];
      s1 += wl;
      s2 += w * nkv_b[c];
      Wk[o * CC + c] = f2bf(wl);
    }
    S1k[o] = s1;
    S2k[o] = s2;
  } else if (which == 2) {
    for (int c = 0; c < CC; ++c) Wv[o * CC + c] = f2bf(v_pw[o * CC + c]);
  } else {
    for (int c = 0; c < CC; ++c) Wproj[o * CC + c] = f2bf(proj_w[o * CC + c]);
  }
}

// ---------------------------------------------------------------------------
// 1. Fused q/k/v conv1x1 (MFMA). blockIdx.z: 0=q(LN,state) 1=k(LN,dark)
//    2=v(dark). Tile M=128 x N=128 px, K=128. 256 thr / 4 waves.
//    Staging: float4 coalesced + quad shuffle-transpose -> swizzled Xs[p][c].
//    Epilogue: acc -> LDS bounce (reuse Xs) -> coalesced u16x8 stores.
// ---------------------------------------------------------------------------
__global__ __launch_bounds__(256) void conv3_kernel(
    const float* __restrict__ state, const float* __restrict__ dark,
    const unsigned short* __restrict__ Wq, const unsigned short* __restrict__ Wk,
    const unsigned short* __restrict__ Wv, const float* __restrict__ S1q,
    const float* __restrict__ S2q, const float* __restrict__ S1k,
    const float* __restrict__ S2k, unsigned short* __restrict__ Cq,
    unsigned short* __restrict__ Ck, unsigned short* __restrict__ Cv) {
  __shared__ unsigned short Xs[128 * 128];  // 32 KiB, [p][c] swizzled (p&7)<<4
  __shared__ float sstat[2][2][128];        // [s|ss][chalf][px]
  __shared__ float muA[128], rrA[128];

  int z = blockIdx.z;
  const float* X = (z == 0) ? state : dark;
  const unsigned short* W = (z == 0) ? Wq : (z == 1) ? Wk : Wv;
  const float* S1 = (z == 0) ? S1q : S1k;
  const float* S2 = (z == 0) ? S2q : S2k;
  unsigned short* Out = (z == 0) ? Cq : (z == 1) ? Ck : Cv;
  const bool do_ln = (z < 2);

  int tid = threadIdx.x;
  int lane = tid & 63, wid = tid >> 6;
  int b = blockIdx.y;
  int p0 = blockIdx.x * 128;

  // ---- staging: 16 iters, quad transposes
  int r = tid & 3;
  int qd = tid >> 2;       // 0..63
  int pg = qd & 31;        // pixel group (4 px)
  int chalf = qd >> 5;     // channel half
  int p = pg * 4 + r;
  size_t xbase = (size_t)b * CC * HW + p0 + pg * 4;
  float s = 0.f, ss = 0.f;
#pragma unroll
  for (int i = 0; i < 16; ++i) {
    int cb = chalf * 4 + i * 8;
    float4 f = *(const float4*)(X + xbase + (size_t)(cb + r) * HW);
    float v0 = f.x, v1 = f.y, v2 = f.z, v3 = f.w;
    quad_transpose(v0, v1, v2, v3, r);
    if (do_ln) {
      s += v0 + v1 + v2 + v3;
      ss += v0 * v0 + v1 * v1 + v2 * v2 + v3 * v3;
    }
    u16x4 o;
    o[0] = f2bf(v0); o[1] = f2bf(v1); o[2] = f2bf(v2); o[3] = f2bf(v3);
    *(u16x4*)((char*)Xs + p * 256 + ((cb * 2) ^ ((p & 7) << 4))) = o;
  }
  if (do_ln) {
    sstat[0][chalf][p] = s;
    sstat[1][chalf][p] = ss;
  }
  __syncthreads();

  if (do_ln && wid == 0) {
#pragma unroll
    for (int t = 0; t < 2; ++t) {
      int px = lane + t * 64;
      float t1 = sstat[0][0][px] + sstat[0][1][px];
      float t2 = sstat[1][0][px] + sstat[1][1][px];
      float mu = t1 * (1.f / 128.f);
      float var = t2 * (1.f / 128.f) - mu * mu;
      muA[px] = mu;
      rrA[px] = rsqrtf(var + 1e-6f);
    }
  }

  // ---- MFMA: each wave does rows [wid*32, wid*32+32), all 128 px
  f32x4 acc[2][8];
#pragma unroll
  for (int mi = 0; mi < 2; ++mi)
#pragma unroll
    for (int n = 0; n < 8; ++n) acc[mi][n] = (f32x4){0.f, 0.f, 0.f, 0.f};

#pragma unroll
  for (int kk = 0; kk < 4; ++kk) {
    int o0 = wid * 32 + (lane & 15);
    s16x8 af0 = *(const s16x8*)(W + (size_t)o0 * CC + kk * 32 + (lane >> 4) * 8);
    s16x8 af1 =
        *(const s16x8*)(W + (size_t)(o0 + 16) * CC + kk * 32 + (lane >> 4) * 8);
#pragma unroll
    for (int n = 0; n < 8; ++n) {
      int pp = n * 16 + (lane & 15);
      int colb = (kk * 64 + (lane >> 4) * 16) ^ ((pp & 7) << 4);
      s16x8 bv = *(s16x8*)((char*)Xs + pp * 256 + colb);
      acc[0][n] = __builtin_amdgcn_mfma_f32_16x16x32_bf16(af0, bv, acc[0][n], 0, 0, 0);
      acc[1][n] = __builtin_amdgcn_mfma_f32_16x16x32_bf16(af1, bv, acc[1][n], 0, 0, 0);
    }
  }
  __syncthreads();  // MFMA reads done; muA/rrA visible; Xs reusable

  // ---- epilogue: LN fold, quad transpose, bounce via Xs[o][p]
  int g = lane >> 4, q = (lane >> 2) & 3, m = lane & 3;
#pragma unroll
  for (int mi = 0; mi < 2; ++mi) {
    int o = wid * 32 + mi * 16 + g * 4 + m;
    float s1v = 0.f, s2v = 0.f;
    if (do_ln) { s1v = S1[o]; s2v = S2[o]; }
#pragma unroll
    for (int n = 0; n < 8; ++n) {
      float v0 = acc[mi][n][0], v1 = acc[mi][n][1], v2 = acc[mi][n][2],
            v3 = acc[mi][n][3];
      quad_transpose(v0, v1, v2, v3, m);
      int px0 = n * 16 + q * 4;
      if (do_ln) {
        float4 muv = *(float4*)&muA[px0];
        float4 rrv = *(float4*)&rrA[px0];
        v0 = rrv.x * (v0 - muv.x * s1v) + s2v;
        v1 = rrv.y * (v1 - muv.y * s1v) + s2v;
        v2 = rrv.z * (v2 - muv.z * s1v) + s2v;
        v3 = rrv.w * (v3 - muv.w * s1v) + s2v;
      }
      u16x4 ov;
      ov[0] = f2bf(v0); ov[1] = f2bf(v1); ov[2] = f2bf(v2); ov[3] = f2bf(v3);
      *(u16x4*)((char*)Xs + o * 256 + ((px0 * 2) ^ ((o & 7) << 4))) = ov;
    }
  }
  __syncthreads();

  // coalesced readback + store: wave stores 4 full rows (256 B each)
#pragma unroll
  for (int it = 0; it < 8; ++it) {
    int row = it * 16 + (tid >> 4);
    int colb = ((tid & 15) * 16) ^ ((row & 7) << 4);
    u16x8 vv = *(u16x8*)((char*)Xs + row * 256 + colb);
    *(u16x8*)(Out + ((size_t)b * CC + row) * HW + p0 + (tid & 15) * 8) = vv;
  }
}

// ---------------------------------------------------------------------------
// 2. proj conv1x1 (MFMA), bf16 in -> fp32 out + residual. Same geometry.
// ---------------------------------------------------------------------------
__global__ __launch_bounds__(256) void proj_kernel(
    const unsigned short* __restrict__ Xin, const unsigned short* __restrict__ Wp,
    const float* __restrict__ res, float* __restrict__ Out) {
  __shared__ unsigned short Xs[128 * 128];

  int tid = threadIdx.x;
  int lane = tid & 63, wid = tid >> 6;
  int b = blockIdx.y;
  int p0 = blockIdx.x * 128;

  int r = tid & 3;
  int qd = tid >> 2;
  int pg = qd & 31;
  int chalf = qd >> 5;
  int p = pg * 4 + r;
  size_t xbase = (size_t)b * CC * HW + p0 + pg * 4;
#pragma unroll
  for (int i = 0; i < 16; ++i) {
    int cb = chalf * 4 + i * 8;
    u16x4 u = *(const u16x4*)(Xin + xbase + (size_t)(cb + r) * HW);
    float v0 = bf2f(u[0]), v1 = bf2f(u[1]), v2 = bf2f(u[2]), v3 = bf2f(u[3]);
    quad_transpose(v0, v1, v2, v3, r);
    u16x4 o;
    o[0] = f2bf(v0); o[1] = f2bf(v1); o[2] = f2bf(v2); o[3] = f2bf(v3);
    *(u16x4*)((char*)Xs + p * 256 + ((cb * 2) ^ ((p & 7) << 4))) = o;
  }
  __syncthreads();

  f32x4 acc[2][8];
#pragma unroll
  for (int mi = 0; mi < 2; ++mi)
#pragma unroll
    for (int n = 0; n < 8; ++n) acc[mi][n] = (f32x4){0.f, 0.f, 0.f, 0.f};

#pragma unroll
  for (int kk = 0; kk < 4; ++kk) {
    int o0 = wid * 32 + (lane & 15);
    s16x8 af0 = *(const s16x8*)(Wp + (size_t)o0 * CC + kk * 32 + (lane >> 4) * 8);
    s16x8 af1 =
        *(const s16x8*)(Wp + (size_t)(o0 + 16) * CC + kk * 32 + (lane >> 4) * 8);
#pragma unroll
    for (int n = 0; n < 8; ++n) {
      int pp = n * 16 + (lane & 15);
      int colb = (kk * 64 + (lane >> 4) * 16) ^ ((pp & 7) << 4);
      s16x8 bv = *(s16x8*)((char*)Xs + pp * 256 + colb);
      acc[0][n] = __builtin_amdgcn_mfma_f32_16x16x32_bf16(af0, bv, acc[0][n], 0, 0, 0);
      acc[1][n] = __builtin_amdgcn_mfma_f32_16x16x32_bf16(af1, bv, acc[1][n], 0, 0, 0);
    }
  }

  // epilogue: quad transpose -> float4 stores (+ residual). 64B/quad: clean.
  int g = lane >> 4, q = (lane >> 2) & 3, m = lane & 3;
#pragma unroll
  for (int mi = 0; mi < 2; ++mi) {
    int o = wid * 32 + mi * 16 + g * 4 + m;
#pragma unroll
    for (int n = 0; n < 8; ++n) {
      float v0 = acc[mi][n][0], v1 = acc[mi][n][1], v2 = acc[mi][n][2],
            v3 = acc[mi][n][3];
      quad_transpose(v0, v1, v2, v3, m);
      int px0 = n * 16 + q * 4;
      size_t off = ((size_t)b * CC + o) * HW + p0 + px0;
      float4 rv = *(const float4*)(res + off);
      float4 ov = {v0 + rv.x, v1 + rv.y, v2 + rv.z, v3 + rv.w};
      *(float4*)(Out + off) = ov;
    }
  }
}

// ---------------------------------------------------------------------------
// 3. Fused q/k/v depthwise 3x3 (strip-tiled). blockIdx.y: 0=q 1=k 2=v.
//    q,k paths also reduce sum-of-squares into rq/rk.
// ---------------------------------------------------------------------------
__global__ __launch_bounds__(256) void dwconv3_kernel(
    const unsigned short* __restrict__ Cq, const unsigned short* __restrict__ Ck,
    const unsigned short* __restrict__ Cv, const float* __restrict__ q_dw,
    const float* __restrict__ k_dw, const float* __restrict__ v_dw,
    unsigned short* __restrict__ Qo, unsigned short* __restrict__ Ko,
    unsigned short* __restrict__ Vo, float* __restrict__ rq,
    float* __restrict__ rk) {
  __shared__ float plane[34 * 128];  // 17 KiB
  int z = blockIdx.y;
  const unsigned short* X = (z == 0) ? Cq : (z == 1) ? Ck : Cv;
  const float* Wd = (z == 0) ? q_dw : (z == 1) ? k_dw : v_dw;
  unsigned short* Out = (z == 0) ? Qo : (z == 1) ? Ko : Vo;
  float* normOut = (z == 0) ? rq : (z == 1) ? rk : nullptr;

  int strip = blockIdx.x & 3;
  int bc = blockIdx.x >> 2;
  int c = bc & (CC - 1);
  int y0 = strip * 32;
  const unsigned short* src = X + (size_t)bc * HW;
  int tid = threadIdx.x;

  for (int idx = tid; idx < 34 * 16; idx += 256) {
    int row = idx >> 4;
    int x8 = (idx & 15) * 8;
    int y = y0 - 1 + row;
    float4 f0 = {0, 0, 0, 0}, f1 = {0, 0, 0, 0};
    if (y >= 0 && y < HH) {
      u16x8 v = *(const u16x8*)(src + (size_t)y * WWID + x8);
      f0 = make_float4(bf2f(v[0]), bf2f(v[1]), bf2f(v[2]), bf2f(v[3]));
      f1 = make_float4(bf2f(v[4]), bf2f(v[5]), bf2f(v[6]), bf2f(v[7]));
    }
    *(float4*)&plane[row * 128 + x8] = f0;
    *(float4*)&plane[row * 128 + x8 + 4] = f1;
  }
  float w[9];
#pragma unroll
  for (int j = 0; j < 9; ++j) w[j] = Wd[c * 9 + j];
  __syncthreads();

  float ssq = 0.f;
  unsigned short* dst = Out + (size_t)bc * HW + y0 * WWID;
#pragma unroll
  for (int i = 0; i < 4; ++i) {
    int pix4 = i * 1024 + tid * 4;
    int ly = pix4 >> 7, x0 = pix4 & 127;
    const float* pc = &plane[(ly + 1) * 128 + x0];
    float sv[4];
    if (x0 >= 4 && x0 <= 120) {
#pragma unroll
      for (int dx = 0; dx < 4; ++dx)
        sv[dx] = w[0] * pc[dx - 129] + w[1] * pc[dx - 128] + w[2] * pc[dx - 127] +
                 w[3] * pc[dx - 1] + w[4] * pc[dx] + w[5] * pc[dx + 1] +
                 w[6] * pc[dx + 127] + w[7] * pc[dx + 128] + w[8] * pc[dx + 129];
    } else {
#pragma unroll
      for (int dx = 0; dx < 4; ++dx) {
        int x = x0 + dx;
        float a = 0.f;
        for (int dy = -1; dy <= 1; ++dy)
          for (int dx2 = -1; dx2 <= 1; ++dx2) {
            int xx = x + dx2;
            if (xx >= 0 && xx < WWID)
              a += w[(dy + 1) * 3 + dx2 + 1] * plane[(ly + 1 + dy) * 128 + xx];
          }
        sv[dx] = a;
      }
    }
    if (normOut) ssq += sv[0] * sv[0] + sv[1] * sv[1] + sv[2] * sv[2] + sv[3] * sv[3];
    u16x4 o;
#pragma unroll
    for (int dx = 0; dx < 4; ++dx) o[dx] = f2bf(sv[dx]);
    *(u16x4*)(dst + pix4) = o;
  }
  if (normOut) {
#pragma unroll
    for (int m2 = 32; m2 >= 1; m2 >>= 1) ssq += __shfl_xor(ssq, m2, 64);
    __shared__ float sred[4];
    if ((tid & 63) == 0) sred[tid >> 6] = ssq;
    __syncthreads();
    if (tid == 0) atomicAdd(&normOut[bc], sred[0] + sred[1] + sred[2] + sred[3]);
  }
}

// ---------------------------------------------------------------------------
// 4a. QK^T partial sums: 32 K-splits of 512 pixels.
// ---------------------------------------------------------------------------
__global__ __launch_bounds__(256) void qk_partial_kernel(
    const unsigned short* __restrict__ Q, const unsigned short* __restrict__ K,
    float* __restrict__ part) {
  __shared__ float qs[32][129];
  __shared__ float ks[32][129];
  int ksid = blockIdx.x;
  int bh = blockIdx.y;
  int b = bh >> 2, h = bh & 3;
  size_t base = ((size_t)b * CC + h * DC) * HW + ksid * 512;
  int tid = threadIdx.x;
  int ci0 = (tid >> 4) * 2, ce0 = (tid & 15) * 2;
  float a00 = 0, a01 = 0, a10 = 0, a11 = 0;
  for (int ch = 0; ch < 4; ++ch) {
#pragma unroll
    for (int i = 0; i < 2; ++i) {
      int idx = i * 256 + tid;
      int rr = idx >> 4, c8 = (idx & 15) * 8;
      u16x8 qv = *(const u16x8*)(Q + base + (size_t)rr * HW + ch * 128 + c8);
      u16x8 kv = *(const u16x8*)(K + base + (size_t)rr * HW + ch * 128 + c8);
#pragma unroll
      for (int j = 0; j < 8; ++j) {
        qs[rr][c8 + j] = bf2f(qv[j]);
        ks[rr][c8 + j] = bf2f(kv[j]);
      }
    }
    __syncthreads();
    for (int pp = 0; pp < 128; ++pp) {
      float q0 = qs[ci0][pp], q1 = qs[ci0 + 1][pp];
      float k0 = ks[ce0][pp], k1 = ks[ce0 + 1][pp];
      a00 += q0 * k0;
      a01 += q0 * k1;
      a10 += q1 * k0;
      a11 += q1 * k1;
    }
    __syncthreads();
  }
  float* o = part + ((size_t)bh * 32 + ksid) * 1024;
  o[ci0 * 32 + ce0] = a00;
  o[ci0 * 32 + ce0 + 1] = a01;
  o[(ci0 + 1) * 32 + ce0] = a10;
  o[(ci0 + 1) * 32 + ce0 + 1] = a11;
}

// ---------------------------------------------------------------------------
// 4b. Reduce partials, scale by temp * rsqrt(ssq), softmax over e.
// ---------------------------------------------------------------------------
__global__ __launch_bounds__(1024) void softmax_kernel(
    const float* __restrict__ part, const float* __restrict__ rq,
    const float* __restrict__ rk, const float* __restrict__ temp,
    float* __restrict__ attn) {
  int bh = blockIdx.x;
  int b = bh >> 2, h = bh & 3;
  int tid = threadIdx.x;
  int c = tid >> 5, e = tid & 31;
  const float* p0 = part + (size_t)bh * 32 * 1024 + tid;
  float s = 0.f;
#pragma unroll
  for (int ks = 0; ks < 32; ++ks) s += p0[(size_t)ks * 1024];
  float nq = sqrtf(rq[b * CC + h * DC + c]);
  float nk = sqrtf(rk[b * CC + h * DC + e]);
  s *= temp[h] / (fmaxf(nq, 1e-12f) * fmaxf(nk, 1e-12f));
  float m = s;
#pragma unroll
  for (int w2 = 16; w2 >= 1; w2 >>= 1) m = fmaxf(m, __shfl_xor(m, w2, 64));
  float pe = __expf(s - m);
  float sum = pe;
#pragma unroll
  for (int w2 = 16; w2 >= 1; w2 >>= 1) sum += __shfl_xor(sum, w2, 64);
  attn[(size_t)bh * 1024 + tid] = pe / sum;
}

// ---------------------------------------------------------------------------
// 5. out[b,h,c,p] = sum_e attn[c,e] * v[b,h,e,p]   (v bf16, out bf16)
// ---------------------------------------------------------------------------
__global__ __launch_bounds__(256) void av_kernel(
    const float* __restrict__ attn, const unsigned short* __restrict__ V,
    unsigned short* __restrict__ Out) {
  __shared__ float vs[32][260];
  __shared__ float as[32][32];
  int pt = blockIdx.x, bh = blockIdx.y;
  int b = bh >> 2, h = bh & 3;
  size_t vbase = ((size_t)b * CC + h * DC) * HW + pt * 256;
  int tid = threadIdx.x;
#pragma unroll
  for (int i = 0; i < 4; ++i) {
    int idx = i * 256 + tid;
    int rr = idx >> 5, c8 = (idx & 31) * 8;
    u16x8 vv = *(const u16x8*)(V + vbase + (size_t)rr * HW + c8);
#pragma unroll
    for (int j = 0; j < 8; ++j) vs[rr][c8 + j] = bf2f(vv[j]);
  }
#pragma unroll
  for (int i = 0; i < 4; ++i)
    ((float*)as)[i * 256 + tid] = attn[(size_t)bh * 1024 + i * 256 + tid];
  __syncthreads();

  int cg = tid >> 6;
  int p4 = (tid & 63) * 4;
  float4 acc[8];
#pragma unroll
  for (int ci = 0; ci < 8; ++ci) acc[ci] = make_float4(0.f, 0.f, 0.f, 0.f);
  for (int e = 0; e < 32; ++e) {
    float4 v4 = *(float4*)&vs[e][p4];
#pragma unroll
    for (int ci = 0; ci < 8; ++ci) {
      float a = as[cg * 8 + ci][e];
      acc[ci].x += a * v4.x;
      acc[ci].y += a * v4.y;
      acc[ci].z += a * v4.z;
      acc[ci].w += a * v4.w;
    }
  }
#pragma unroll
  for (int ci = 0; ci < 8; ++ci) {
    size_t off = ((size_t)b * CC + h * DC + cg * 8 + ci) * HW + pt * 256 + p4;
    u16x4 o;
    o[0] = f2bf(acc[ci].x);
    o[1] = f2bf(acc[ci].y);
    o[2] = f2bf(acc[ci].z);
    o[3] = f2bf(acc[ci].w);
    *(u16x4*)(Out + off) = o;
  }
}

// ---------------------------------------------------------------------------
extern "C" void kernel_launch(void* const* d_in, const int* in_sizes, int n_in,
                              void* d_out, int out_size, void* d_ws, size_t ws_size,
                              hipStream_t stream) {
  (void)in_sizes; (void)n_in; (void)out_size; (void)ws_size;
  const float* state = (const float*)d_in[0];
  const float* dark = (const float*)d_in[1];
  const float* nq_w = (const float*)d_in[2];
  const float* nq_b = (const float*)d_in[3];
  const float* nkv_w = (const float*)d_in[4];
  const float* nkv_b = (const float*)d_in[5];
  const float* q_pw = (const float*)d_in[6];
  const float* q_dw = (const float*)d_in[7];
  const float* k_pw = (const float*)d_in[8];
  const float* k_dw = (const float*)d_in[9];
  const float* v_pw = (const float*)d_in[10];
  const float* v_dw = (const float*)d_in[11];
  const float* proj_w = (const float*)d_in[12];
  const float* temp = (const float*)d_in[13];
  float* out = (float*)d_out;

  // Workspace: 6 x 32 MiB bf16 buffers + small region (~197 MiB total)
  char* ws = (char*)d_ws;
  const size_t REG = 32ull << 20;
  unsigned short* R0 = (unsigned short*)(ws + 0 * REG);  // Cq, later av-out
  unsigned short* R1 = (unsigned short*)(ws + 1 * REG);  // Q
  unsigned short* R2 = (unsigned short*)(ws + 2 * REG);  // Ck
  unsigned short* R3 = (unsigned short*)(ws + 3 * REG);  // Cv
  unsigned short* R4 = (unsigned short*)(ws + 4 * REG);  // K
  unsigned short* R5 = (unsigned short*)(ws + 5 * REG);  // V
  char* sm = ws + 6 * REG;
  float* part = (float*)sm; sm += (size_t)32 * 32 * 1024 * 4;  // 4 MiB
  float* attn = (float*)sm; sm += (size_t)32 * 1024 * 4;
  float* rq = (float*)sm; sm += BB * CC * 4;  // sumsq(q) per row
  float* rk = (float*)sm; sm += BB * CC * 4;  // sumsq(k) per row
  unsigned short* Wq = (unsigned short*)sm; sm += (size_t)CC * CC * 2;
  unsigned short* Wk = (unsigned short*)sm; sm += (size_t)CC * CC * 2;
  unsigned short* Wv = (unsigned short*)sm; sm += (size_t)CC * CC * 2;
  unsigned short* Wproj = (unsigned short*)sm; sm += (size_t)CC * CC * 2;
  float* S1q = (float*)sm; sm += CC * 4;
  float* S2q = (float*)sm; sm += CC * 4;
  float* S1k = (float*)sm; sm += CC * 4;
  float* S2k = (float*)sm; sm += CC * 4;

  hipMemsetAsync(rq, 0, 2 * BB * CC * sizeof(float), stream);

  prep_weights_kernel<<<dim3(4), 128, 0, stream>>>(
      q_pw, k_pw, v_pw, proj_w, nq_w, nq_b, nkv_w, nkv_b, Wq, Wk, Wv, Wproj,
      S1q, S2q, S1k, S2k);

  // fused q/k/v 1x1 convs (LN folded for q,k)
  conv3_kernel<<<dim3(HW / 128, BB, 3), 256, 0, stream>>>(
      state, dark, Wq, Wk, Wv, S1q, S2q, S1k, S2k, R0, R2, R3);

  // fused q/k/v depthwise convs (+ norms for q,k)
  dwconv3_kernel<<<dim3(BB * CC * 4, 3), 256, 0, stream>>>(
      R0, R2, R3, q_dw, k_dw, v_dw, R1, R4, R5, rq, rk);

  // attention logits + softmax
  qk_partial_kernel<<<dim3(32, BB * NHEADS), 256, 0, stream>>>(R1, R4, part);
  softmax_kernel<<<dim3(BB * NHEADS), 1024, 0, stream>>>(part, rq, rk, temp, attn);

  // attn @ v -> R0
  av_kernel<<<dim3(HW / 256, BB * NHEADS), 256, 0, stream>>>(attn, R5, R0);

  // projection + residual (bf16 in, f32 out)
  proj_kernel<<<dim3(HW / 128, BB), 256, 0, stream>>>(R0, Wproj, state, out);
}